// Round 1
// baseline (1136.136 us; speedup 1.0000x reference)
//
#include <hip/hip_runtime.h>
#include <math.h>

// FractionalDilationR2: out[b,c,y,x] = max_{dy,dx in [-5,5]} u[b,c,y+dy,x+dx] - k[c,dy+5,dx+5]
// k_c = nu * rho^e * exp(-e * sum_j p[c,j] B_j(theta)),  e = 2a/(2a-1), a=0.65.
// Out-of-bounds u treated as -1e30.

#define RR 5
#define KS 11
#define NTAPS (KS * KS)     // 121
#define HDIM 512
#define WDIM 512
#define NCH 32
#define TX 64               // output tile width (= lanes in x)
#define TY 32               // output tile height per iteration
#define VPT 8               // vertical outputs per thread (TY / blockDim.y)
#define TH (TY + 2 * RR)    // 42 tile rows in LDS
#define TW (TX + 2 * RR)    // 74 tile cols
#define PITCH 76            // padded LDS pitch (floats)
#define NEGF (-1e30f)

__global__ __launch_bounds__(256, 2) void frac_dilation_kernel(
    const float* __restrict__ u,
    const float* __restrict__ finsler,   // [32,6]
    float* __restrict__ out)
{
    __shared__ float klds[NTAPS];
    __shared__ float tile[TH * PITCH];

    const int tx  = threadIdx.x;          // 0..63
    const int ty  = threadIdx.y;          // 0..3
    const int tid = ty * 64 + tx;
    const int p   = blockIdx.y;           // plane index b*32+c, 0..255
    const int c   = p & (NCH - 1);
    const int ox  = blockIdx.x * TX;

    // ---- per-block: compute the 121 per-channel kernel values (double, once) ----
    if (tid < NTAPS) {
        const int dy = tid / KS - RR;     // y offset (meshgrid 'ij': first axis)
        const int dx = tid % KS - RR;
        const double rho = sqrt((double)(dx * dx + dy * dy));
        const double th  = atan2((double)dy, (double)dx);
        const float* pc = finsler + c * 6;
        const double g =
            (double)pc[0] * cos(th)       + (double)pc[1] * sin(th) +
            (double)pc[2] * cos(2.0 * th) + (double)pc[3] * sin(2.0 * th) +
            (double)pc[4] * cos(3.0 * th) + (double)pc[5] * sin(3.0 * th);
        const double e  = 2.0 * 0.65 / (2.0 * 0.65 - 1.0);     // 13/3
        const double nu = (2.0 * 0.65 - 1.0) * pow(2.0 * 0.65, -e);
        const double kvd = (rho == 0.0) ? 0.0 : nu * pow(rho, e) * exp(-e * g);
        klds[tid] = (float)kvd;
    }
    __syncthreads();

    // hold all 121 kernel values in VGPRs for the whole strip
    float kv[NTAPS];
#pragma unroll
    for (int i = 0; i < NTAPS; ++i) kv[i] = klds[i];

    const float* uplane = u   + (size_t)p * (HDIM * WDIM);
    float*       oplane = out + (size_t)p * (HDIM * WDIM);

    const int y0 = ty * VPT;  // local row of this thread's first output (0,8,16,24)

#pragma unroll 1
    for (int itY = 0; itY < HDIM / TY; ++itY) {
        const int oy = itY * TY;

        __syncthreads();   // previous iteration's compute must finish before reload
        // ---- stage tile + halo into LDS, NEG outside the plane ----
#pragma unroll 1
        for (int r = ty; r < TH; r += 4) {
            const int gy = oy + r - RR;
            const bool yok = (gy >= 0) & (gy < HDIM);
#pragma unroll 1
            for (int cc = tx; cc < TW; cc += 64) {
                const int gx = ox + cc - RR;
                float v = NEGF;
                if (yok && gx >= 0 && gx < WDIM) v = uplane[gy * WDIM + gx];
                tile[r * PITCH + cc] = v;
            }
        }
        __syncthreads();

        // ---- 121-tap max over the register-blocked column ----
        float acc[VPT];
#pragma unroll
        for (int i = 0; i < VPT; ++i) acc[i] = NEGF;

#pragma unroll
        for (int dx = 0; dx < KS; ++dx) {
            float col[VPT + KS - 1];           // 18 column values
#pragma unroll
            for (int r2 = 0; r2 < VPT + KS - 1; ++r2)
                col[r2] = tile[(y0 + r2) * PITCH + tx + dx];
#pragma unroll
            for (int dy = 0; dy < KS; ++dy) {
                const float kvv = kv[dy * KS + dx];
#pragma unroll
                for (int i = 0; i < VPT; ++i)
                    acc[i] = fmaxf(acc[i], col[dy + i] - kvv);
            }
        }

        // ---- store ----
#pragma unroll
        for (int i = 0; i < VPT; ++i)
            oplane[(oy + y0 + i) * WDIM + ox + tx] = acc[i];
    }
}

extern "C" void kernel_launch(void* const* d_in, const int* in_sizes, int n_in,
                              void* d_out, int out_size, void* d_ws, size_t ws_size,
                              hipStream_t stream) {
    const float* u  = (const float*)d_in[0];   // (8,32,512,512) fp32
    const float* fp = (const float*)d_in[1];   // (32,6) fp32
    float* out = (float*)d_out;

    dim3 grid(WDIM / TX, 8 * NCH);   // 8 x-strips, 256 planes
    dim3 block(64, 4);
    frac_dilation_kernel<<<grid, block, 0, stream>>>(u, fp, out);
}

// Round 2
// 713.478 us; speedup vs baseline: 1.5924x; 1.5924x over previous
//
#include <hip/hip_runtime.h>
#include <math.h>

// FractionalDilationR2: out[b,c,y,x] = max_{dy,dx in [-5,5]} u[b,c,y+dy,x+dx] - k[c,dy+5,dx+5]
// k_c = nu * rho^e * exp(-e * sum_j p[c,j] B_j(theta)),  e = 2a/(2a-1), a = 0.65 (e = 13/3).
//
// Exact pruning: center tap has k=0, so acc >= u[p] >= tileMin. Any tap with
// k >= tileMax - tileMin (valid values only) can never exceed acc -> drop it.
// Per dx column we keep a contiguous [lo,hi] dy-hull of live taps (conservative,
// always correct; full range when delta is large).

#define RR 5
#define KS 11
#define NTAPS (KS * KS)     // 121
#define HDIM 512
#define WDIM 512
#define NCH 32
#define TX 64               // output tile width (= lanes in x)
#define TY 32               // output tile height per iteration
#define VPT 8               // vertical outputs per thread
#define TH (TY + 2 * RR)    // 42 tile rows in LDS
#define TW (TX + 2 * RR)    // 74 tile cols
#define PITCH 76            // padded LDS pitch (floats)
#define NEGF (-1e30f)

// ---- pre-kernel: build the 32x121 kernel table in double, once per launch ----
__global__ void build_ktab_kernel(const float* __restrict__ finsler,
                                  float* __restrict__ ktab) {
    const int c = blockIdx.x;          // 0..31
    const int t = threadIdx.x;         // 0..127
    if (t >= NTAPS) return;
    const int dy = t / KS - RR;
    const int dx = t % KS - RR;
    const double rho = sqrt((double)(dx * dx + dy * dy));
    const double th  = atan2((double)dy, (double)dx);
    const float* pc = finsler + c * 6;
    const double g =
        (double)pc[0] * cos(th)       + (double)pc[1] * sin(th) +
        (double)pc[2] * cos(2.0 * th) + (double)pc[3] * sin(2.0 * th) +
        (double)pc[4] * cos(3.0 * th) + (double)pc[5] * sin(3.0 * th);
    const double e  = 2.0 * 0.65 / (2.0 * 0.65 - 1.0);     // 13/3
    const double nu = (2.0 * 0.65 - 1.0) * pow(2.0 * 0.65, -e);
    const double kvd = (rho == 0.0) ? 0.0 : nu * pow(rho, e) * exp(-e * g);
    ktab[c * NTAPS + t] = (float)kvd;
}

__global__ __launch_bounds__(256, 4) void frac_dilation_kernel(
    const float* __restrict__ u,
    const float* __restrict__ ktab,    // [32,121] precomputed
    float* __restrict__ out)
{
    __shared__ float klds[NTAPS];
    __shared__ float tile[TH * PITCH];
    __shared__ float wmaxs[4], wmins[4];
    __shared__ int   lohi_lds[KS];

    const int tx  = threadIdx.x;          // 0..63
    const int ty  = threadIdx.y;          // 0..3
    const int tid = ty * 64 + tx;
    const int p   = blockIdx.y;           // plane index b*32+c
    const int c   = p & (NCH - 1);
    const int ox  = blockIdx.x * TX;

    if (tid < NTAPS) klds[tid] = ktab[c * NTAPS + tid];
    // visible after the first __syncthreads below

    const float* uplane = u   + (size_t)p * (HDIM * WDIM);
    float*       oplane = out + (size_t)p * (HDIM * WDIM);
    const int y0 = ty * VPT;              // this thread's first output row (local)

#pragma unroll 1
    for (int itY = 0; itY < HDIM / TY; ++itY) {
        const int oy = itY * TY;

        __syncthreads();   // A: previous compute must finish before tile reload

        // ---- stage tile + halo, tracking valid-value min/max ----
        float vmax = -3.0e38f, vmin = 3.0e38f;
#pragma unroll 1
        for (int r = ty; r < TH; r += 4) {
            const int gy = oy + r - RR;
            const bool yok = (gy >= 0) & (gy < HDIM);
#pragma unroll 1
            for (int cc = tx; cc < TW; cc += 64) {
                const int gx = ox + cc - RR;
                float v = NEGF;
                if (yok && gx >= 0 && gx < WDIM) {
                    v = uplane[gy * WDIM + gx];
                    vmax = fmaxf(vmax, v);
                    vmin = fminf(vmin, v);
                }
                tile[r * PITCH + cc] = v;
            }
        }
        // wave-level reduce (width 64)
#pragma unroll
        for (int m = 1; m < 64; m <<= 1) {
            vmax = fmaxf(vmax, __shfl_xor(vmax, m, 64));
            vmin = fminf(vmin, __shfl_xor(vmin, m, 64));
        }
        if (tx == 0) { wmaxs[ty] = vmax; wmins[ty] = vmin; }
        __syncthreads();   // B: tile + wave partials visible

        const float tmax = fmaxf(fmaxf(wmaxs[0], wmaxs[1]), fmaxf(wmaxs[2], wmaxs[3]));
        const float tmin = fminf(fminf(wmins[0], wmins[1]), fminf(wmins[2], wmins[3]));
        const float delta = tmax - tmin;   // >= 0; center tap k=0 always live

        if (tid < KS) {                    // one thread per dx: contiguous dy hull
            int lo = 1, hi = 0;
#pragma unroll
            for (int dy = 0; dy < KS; ++dy) {
                if (klds[dy * KS + tid] <= delta) { if (lo > hi) lo = dy; hi = dy; }
            }
            lohi_lds[tid] = lo | (hi << 16);
        }
        __syncthreads();   // C: hulls visible

        // ---- pruned max-plus accumulation ----
        float acc[VPT];
#pragma unroll
        for (int i = 0; i < VPT; ++i) acc[i] = NEGF;

#pragma unroll
        for (int dx = 0; dx < KS; ++dx) {
            const int lh = __builtin_amdgcn_readfirstlane(lohi_lds[dx]);
            const int lo = lh & 0xffff;
            const int hi = lh >> 16;
#pragma unroll 1
            for (int dy = lo; dy <= hi; ++dy) {
                const float kvv = klds[dy * KS + dx];
                const float* cp = &tile[(y0 + dy) * PITCH + tx + dx];
#pragma unroll
                for (int i = 0; i < VPT; ++i)
                    acc[i] = fmaxf(acc[i], cp[i * PITCH] - kvv);
            }
        }

        // ---- store ----
#pragma unroll
        for (int i = 0; i < VPT; ++i)
            oplane[(oy + y0 + i) * WDIM + ox + tx] = acc[i];
    }
}

extern "C" void kernel_launch(void* const* d_in, const int* in_sizes, int n_in,
                              void* d_out, int out_size, void* d_ws, size_t ws_size,
                              hipStream_t stream) {
    const float* u  = (const float*)d_in[0];   // (8,32,512,512) fp32
    const float* fp = (const float*)d_in[1];   // (32,6) fp32
    float* out  = (float*)d_out;
    float* ktab = (float*)d_ws;                // 32*121 floats = 15.5 KB scratch

    build_ktab_kernel<<<dim3(NCH), dim3(128), 0, stream>>>(fp, ktab);

    dim3 grid(WDIM / TX, 8 * NCH);   // 8 x-strips, 256 planes
    dim3 block(64, 4);
    frac_dilation_kernel<<<grid, block, 0, stream>>>(u, ktab, out);
}